// Round 12
// baseline (249.075 us; speedup 1.0000x reference)
//
#include <hip/hip_runtime.h>

// MADE / PixelCNN autoregressive inverse (all fp32, per reference).
//
// Ledger: r0-r4 6-bar/16-wave ~191-179us (inner-loop invariant). r7
// 2-bar/8-wave spine+helpers 146.5. r9 DOTU==readlane -> MAC style
// irrelevant. r10 2-wave deep chain 229 -> chain stays on one wave. r11
// availability-rebalanced helpers 137.8 (WRITE 33KB, clean). Barrier-count
// elimination bought ~300cy/barrier only; slot time tracks MAX-PHASE
// INSTRUCTION ISSUE.
//
// r12: flatten phases to one dot per wave per phase. 12 waves (3/SIMD,
// ~170-VGPR cap). Per net: S, T(twin), H0,H1,H2 (tap helpers), H4.
//  S : pre: epi(p-1) [y in-reg], h0(p), c1-halfA (readlane q0..7 on own h0v)
//      post: h1 = elu(c1A+c1B+b + 4 W1 partials), c2 (readlane), h2,
//            butterfly, xchg, lsacc.
//  T : pre: epi+h0 CLONES (identical inputs/op order -> bit-identical h0v,
//      no LDS write), c1-halfB (q8..15) -> c1h.
//      post: W1-W . h0(p) for p+1 via readlane on own h0v -> r1w[(p+1)&1].
//  Hk (k=0,1,2 = NW,N,NE): pre: W2(k) . h1row[prv][j+k] -> r2n[k]
//      post: W1(k) . h0row[sp][j2+k] for p+1 -> r1n[k][(p+1)&1]  (i2>=1)
//  H4: pre: W2-W . h1row[cur][j] (pad col 0 -> auto-zero at j==0) -> r2w.
//      post: idle (barriers only).
// Max non-spine phase ~140 instr; spine post (~190) is the binding phase.
// W1 partials parity-double-buffered (write slot p for p+1, read post-B1 of
// p+1); W2 partials + c1h single-buffered (write pre-B1, read post-B1).

#define NT 768

__device__ __forceinline__ float elu(float x) { return x > 0.f ? x : expm1f(x); }

__device__ __forceinline__ float rdlane(float v, int l) {
  return __int_as_float(__builtin_amdgcn_readlane(__float_as_int(v), l));
}

#define BAR() asm volatile("s_waitcnt lgkmcnt(0)\n\ts_barrier" ::: "memory")

// one 64-dot: acc{0..3} += W_[4q+m] * (lane-q broadcast of F_ members)
#define DOT16(W_, F_)                                                \
  _Pragma("unroll")                                                  \
  for (int q = 0; q < 16; ++q) {                                     \
    a0 += (W_)[4*q+0] * rdlane((F_).x, q);                           \
    a1 += (W_)[4*q+1] * rdlane((F_).y, q);                           \
    a2 += (W_)[4*q+2] * rdlane((F_).z, q);                           \
    a3 += (W_)[4*q+3] * rdlane((F_).w, q);                           \
  }

#define FRAG(P_) (reinterpret_cast<const float4*>(P_)[ch & 15])

// shared epilogue math for S and T (identical op order -> identical bits)
#define EPI_CALC(PP_)                                                            \
  const float4 m4 = *reinterpret_cast<const float4*>(&xchg[(PP_) & 1][0][0]);    \
  const float4 l4 = *reinterpret_cast<const float4*>(&xchg[(PP_) & 1][1][0]);    \
  const float ls0 = 0.5f*(l4.x + boL[0]), ls1 = 0.5f*(l4.y + boL[1]);            \
  const float ls2 = 0.5f*(l4.z + boL[2]), ls3 = 0.5f*(l4.w + boL[3]);            \
  y0 = (xls[0*64+(PP_)] - (m4.x + boM[0])) / (expf(ls0) + 1e-12f);               \
  y1 = (xls[1*64+(PP_)] - (m4.y + boM[1])) / (expf(ls1) + 1e-12f);               \
  y2 = (xls[2*64+(PP_)] - (m4.z + boM[2])) / (expf(ls2) + 1e-12f);               \
  y3 = (xls[3*64+(PP_)] - (m4.w + boM[3])) / (expf(ls3) + 1e-12f);

// h0 from yb N-taps + in-register W-tap (identical for S and T)
#define H0_CALC()                                                                \
  float acc = bA;                                                                \
  {                                                                              \
    const float4 yNW = *reinterpret_cast<const float4*>(&yb[net][i][j    ][0]);  \
    const float4 yN  = *reinterpret_cast<const float4*>(&yb[net][i][j + 1][0]);  \
    const float4 yNE = *reinterpret_cast<const float4*>(&yb[net][i][j + 2][0]);  \
    acc += w0t[0]*yNW.x + w0t[1]*yNW.y + w0t[2]*yNW.z + w0t[3]*yNW.w;            \
    acc += w0t[4]*yN.x  + w0t[5]*yN.y  + w0t[6]*yN.z  + w0t[7]*yN.w;             \
    acc += w0t[8]*yNE.x + w0t[9]*yNE.y + w0t[10]*yNE.z + w0t[11]*yNE.w;          \
    if (j > 0) acc += w0t[12]*y0 + w0t[13]*y1 + w0t[14]*y2 + w0t[15]*y3;         \
  }                                                                              \
  const float h0v = elu(acc);

__global__ __launch_bounds__(NT)
__attribute__((amdgpu_waves_per_eu(3, 3)))
void made_ar_decode_k(
    const float* __restrict__ x,
    const float* __restrict__ mw0, const float* __restrict__ mb0,
    const float* __restrict__ mw1, const float* __restrict__ mb1,
    const float* __restrict__ mw2, const float* __restrict__ mb2,
    const float* __restrict__ mwo, const float* __restrict__ mbo,
    const float* __restrict__ lw0, const float* __restrict__ lb0,
    const float* __restrict__ lw1, const float* __restrict__ lb1,
    const float* __restrict__ lw2, const float* __restrict__ lb2,
    const float* __restrict__ lwo, const float* __restrict__ lbo,
    float* __restrict__ out)
{
  const int b    = blockIdx.x;
  const int tid  = threadIdx.x;
  const int wv   = tid >> 6;       // 0..11
  const int net  = wv & 1;         // 0 = mu, 1 = lv
  const int role = wv >> 1;        // 0:S 1:T 2:H0 3:H1 4:H2 5:H4
  const int ch   = tid & 63;       // lane == out channel

  // parity double-buffered row caches; pcol = spatial col + 1; pad cols 0,9
  // never written -> permanent zeros ('SAME' border).
  __shared__ __align__(16) float h0row[2][2][10][64]; // [net][par][pcol][ch]
  __shared__ __align__(16) float h1row[2][2][10][64];
  __shared__ __align__(16) float yb[2][9][10][4];     // [net][prow][pcol][c]
  __shared__ __align__(16) float xchg[2][2][4];       // [p&1][net][c]
  __shared__ float c1h[2][64];                        // T's c1 half (q8..15)
  __shared__ float r1n[3][2][2][64];  // W1 {NW,N,NE} [tap][pix&1][net][ch]
  __shared__ float r1w[2][2][64];     // W1 W         [pix&1][net][ch]
  __shared__ float r2n[3][2][64];     // W2 {NW,N,NE} [tap][net][ch]
  __shared__ float r2w[2][64];        // W2 W         [net][ch]
  __shared__ float xls[256];

  for (int k = tid; k < 2*2*10*64; k += NT) {
    (&h0row[0][0][0][0])[k] = 0.f;
    (&h1row[0][0][0][0])[k] = 0.f;
  }
  for (int k = tid; k < 2*9*10*4; k += NT) (&yb[0][0][0][0])[k] = 0.f;
  for (int k = tid; k < 3*2*2*64; k += NT) (&r1n[0][0][0][0])[k] = 0.f;
  for (int k = tid; k < 2*2*64; k += NT) (&r1w[0][0][0])[k] = 0.f;
  if (tid < 256) xls[tid] = x[b*256 + tid];   // [c][i][j] flat = c*64 + p

  __syncthreads();   // uniform join after init

  if (role == 0) {
    // ================= S: serial spine =================
    const float* w0g = net ? lw0 : mw0;
    const float* w1g = net ? lw1 : mw1;
    const float* w2g = net ? lw2 : mw2;
    const float* wog = net ? lwo : mwo;
    float w0t[16], wc1a[32], wc2[64], wo4[4];
    {
      const int KH[4] = {0,0,0,1};
      const int KW[4] = {0,1,2,0};
#pragma unroll
      for (int t = 0; t < 4; ++t)
#pragma unroll
        for (int ic = 0; ic < 4; ++ic)
          w0t[t*4+ic] = w0g[((ch*4 + ic)*3 + KH[t])*3 + KW[t]];
    }
#pragma unroll
    for (int q = 0; q < 32; ++q) wc1a[q] = w1g[((ch*64 + q)*3 + 1)*3 + 1];
#pragma unroll
    for (int q = 0; q < 64; ++q) wc2[q] = w2g[((ch*64 + q)*3 + 1)*3 + 1];
#pragma unroll
    for (int c = 0; c < 4; ++c) wo4[c] = wog[c*64 + ch];
    const float bA = (net ? lb0 : mb0)[ch];
    const float bB = (net ? lb1 : mb1)[ch];
    const float bC = (net ? lb2 : mb2)[ch];
    float boM[4], boL[4];
#pragma unroll
    for (int c = 0; c < 4; ++c) { boM[c] = mbo[c]; boL[c] = lbo[c]; }
#pragma unroll
    for (int k = 0; k < 16; ++k) asm volatile("" : "+v"(w0t[k]));
#pragma unroll
    for (int q = 0; q < 32; ++q) asm volatile("" : "+v"(wc1a[q]));
#pragma unroll
    for (int q = 0; q < 64; ++q) asm volatile("" : "+v"(wc2[q]));

    float y0 = 0.f, y1 = 0.f, y2 = 0.f, y3 = 0.f;
    float lsacc = 0.f;

#pragma unroll 1
    for (int p = 0; p < 64; ++p) {
      const int i = p >> 3, j = p & 7, cur = i & 1, pb = p & 1;

      // ---- pre-B1: epi(p-1), h0(p), c1-halfA ----
      if (p > 0) {
        const int pp = p - 1;
        EPI_CALC(pp);
        if (ch == 0)
          *reinterpret_cast<float4*>(&yb[net][(pp>>3)+1][(pp&7)+1][0]) =
              make_float4(y0, y1, y2, y3);
      }
      H0_CALC();
      h0row[net][cur][j + 1][ch] = h0v;

      float c1A;
      {
        float a0 = 0.f, a1 = 0.f, a2 = 0.f, a3 = 0.f;
#pragma unroll
        for (int q = 0; q < 8; ++q) {
          a0 += wc1a[4*q+0] * rdlane(h0v, 4*q+0);
          a1 += wc1a[4*q+1] * rdlane(h0v, 4*q+1);
          a2 += wc1a[4*q+2] * rdlane(h0v, 4*q+2);
          a3 += wc1a[4*q+3] * rdlane(h0v, 4*q+3);
        }
        c1A = (a0 + a1) + (a2 + a3);
      }

      BAR();   // B1

      // ---- post-B1: h1, c2, h2, out-conv ----
      const float c1 = c1A + c1h[net][ch];
      const float h1v = elu(((c1 + bB) + (r1n[0][pb][net][ch] + r1n[1][pb][net][ch]))
                            + (r1n[2][pb][net][ch] + r1w[pb][net][ch]));
      h1row[net][cur][j + 1][ch] = h1v;

      float c2;
      {
        float a0 = 0.f, a1 = 0.f, a2 = 0.f, a3 = 0.f;
#pragma unroll
        for (int q = 0; q < 16; ++q) {
          a0 += wc2[4*q+0] * rdlane(h1v, 4*q+0);
          a1 += wc2[4*q+1] * rdlane(h1v, 4*q+1);
          a2 += wc2[4*q+2] * rdlane(h1v, 4*q+2);
          a3 += wc2[4*q+3] * rdlane(h1v, 4*q+3);
        }
        c2 = (a0 + a1) + (a2 + a3);
      }
      const float h2v = elu(((c2 + bC) + (r2n[0][net][ch] + r2n[1][net][ch]))
                            + (r2n[2][net][ch] + r2w[net][ch]));

      float s0 = wo4[0]*h2v, s1 = wo4[1]*h2v, s2 = wo4[2]*h2v, s3 = wo4[3]*h2v;
#pragma unroll
      for (int off = 32; off; off >>= 1) {
        s0 += __shfl_xor(s0, off, 64);
        s1 += __shfl_xor(s1, off, 64);
        s2 += __shfl_xor(s2, off, 64);
        s3 += __shfl_xor(s3, off, 64);
      }
      if (ch == 0)
        *reinterpret_cast<float4*>(&xchg[p & 1][net][0]) = make_float4(s0, s1, s2, s3);
      if (net == 1 && ch == 0)
        lsacc += 0.5f*((s0 + boL[0]) + (s1 + boL[1]) + (s2 + boL[2]) + (s3 + boL[3]));

      BAR();   // B2
    }

    // final y(63) into yb (for the copy-out)
    {
      float y0f, y1f, y2f, y3f;
      {
        float y0, y1, y2, y3;
        EPI_CALC(63);
        y0f = y0; y1f = y1; y2f = y2; y3f = y3;
      }
      if (ch == 0)
        *reinterpret_cast<float4*>(&yb[net][8][8][0]) = make_float4(y0f, y1f, y2f, y3f);
    }
    if (net == 1 && ch == 0) out[32*4*64 + b] = lsacc;

  } else if (role == 1) {
    // ============ T: twin (epi+h0 clones, c1-halfB, W1-W tap) ============
    const float* w0g = net ? lw0 : mw0;
    const float* w1g = net ? lw1 : mw1;
    float w0t[16], wc1b[32], w1w[64];
    {
      const int KH[4] = {0,0,0,1};
      const int KW[4] = {0,1,2,0};
#pragma unroll
      for (int t = 0; t < 4; ++t)
#pragma unroll
        for (int ic = 0; ic < 4; ++ic)
          w0t[t*4+ic] = w0g[((ch*4 + ic)*3 + KH[t])*3 + KW[t]];
    }
#pragma unroll
    for (int q = 0; q < 32; ++q) wc1b[q] = w1g[((ch*64 + (32+q))*3 + 1)*3 + 1];
#pragma unroll
    for (int q = 0; q < 64; ++q) w1w[q] = w1g[((ch*64 + q)*3 + 1)*3 + 0];
    const float bA = (net ? lb0 : mb0)[ch];
    float boM[4], boL[4];
#pragma unroll
    for (int c = 0; c < 4; ++c) { boM[c] = mbo[c]; boL[c] = lbo[c]; }
#pragma unroll
    for (int k = 0; k < 16; ++k) asm volatile("" : "+v"(w0t[k]));
#pragma unroll
    for (int q = 0; q < 32; ++q) asm volatile("" : "+v"(wc1b[q]));
#pragma unroll
    for (int q = 0; q < 64; ++q) asm volatile("" : "+v"(w1w[q]));

    float y0 = 0.f, y1 = 0.f, y2 = 0.f, y3 = 0.f;

#pragma unroll 1
    for (int p = 0; p < 64; ++p) {
      const int i = p >> 3, j = p & 7;

      // ---- pre-B1: epi/h0 clones (bit-identical to S), c1-halfB ----
      if (p > 0) { const int pp = p - 1; EPI_CALC(pp); }
      H0_CALC();

      {
        float a0 = 0.f, a1 = 0.f, a2 = 0.f, a3 = 0.f;
#pragma unroll
        for (int q = 0; q < 8; ++q) {
          a0 += wc1b[4*q+0] * rdlane(h0v, 32 + 4*q+0);
          a1 += wc1b[4*q+1] * rdlane(h0v, 32 + 4*q+1);
          a2 += wc1b[4*q+2] * rdlane(h0v, 32 + 4*q+2);
          a3 += wc1b[4*q+3] * rdlane(h0v, 32 + 4*q+3);
        }
        c1h[net][ch] = (a0 + a1) + (a2 + a3);
      }

      BAR();   // B1

      // ---- post-B1: W1-W . h0(p) for p+1 (own registers) ----
      if (p < 63) {
        const int p2 = p + 1, j2 = p2 & 7;
        float v = 0.f;
        if (j2 > 0) {
          float a0 = 0.f, a1 = 0.f, a2 = 0.f, a3 = 0.f;
#pragma unroll
          for (int q = 0; q < 16; ++q) {
            a0 += w1w[4*q+0] * rdlane(h0v, 4*q+0);
            a1 += w1w[4*q+1] * rdlane(h0v, 4*q+1);
            a2 += w1w[4*q+2] * rdlane(h0v, 4*q+2);
            a3 += w1w[4*q+3] * rdlane(h0v, 4*q+3);
          }
          v = (a0 + a1) + (a2 + a3);
        }
        r1w[p2 & 1][net][ch] = v;
      }

      BAR();   // B2
    }

  } else if (role <= 4) {
    // ============ Hk (k = role-2): W2(k) pre ; W1(k) post for p+1 ============
    const int tap = role - 2;        // 0:NW 1:N 2:NE
    const float* w1g = net ? lw1 : mw1;
    const float* w2g = net ? lw2 : mw2;
    float w2c[64], w1c[64];
#pragma unroll
    for (int q = 0; q < 64; ++q) {
      w2c[q] = w2g[((ch*64 + q)*3 + 0)*3 + tap];
      w1c[q] = w1g[((ch*64 + q)*3 + 0)*3 + tap];
    }
#pragma unroll
    for (int q = 0; q < 64; ++q) {
      asm volatile("" : "+v"(w2c[q]));
      asm volatile("" : "+v"(w1c[q]));
    }
#pragma unroll 1
    for (int p = 0; p < 64; ++p) {
      const int i = p >> 3, j = p & 7, prv = (i & 1) ^ 1;
      {
        const float4 f = FRAG(&h1row[net][prv][j + tap][0]);
        float a0 = 0.f, a1 = 0.f, a2 = 0.f, a3 = 0.f;
        DOT16(w2c, f);
        r2n[tap][net][ch] = (a0 + a1) + (a2 + a3);
      }
      BAR();
      if (p < 63) {
        const int p2 = p + 1, i2 = p2 >> 3, j2 = p2 & 7;
        float v = 0.f;
        if (i2 >= 1) {
          const int sp = (i2 - 1) & 1;
          const float4 f = FRAG(&h0row[net][sp][j2 + tap][0]);
          float a0 = 0.f, a1 = 0.f, a2 = 0.f, a3 = 0.f;
          DOT16(w1c, f);
          v = (a0 + a1) + (a2 + a3);
        }
        r1n[tap][p2 & 1][net][ch] = v;
      }
      BAR();
    }

  } else {
    // ============ H4: W2-W . h1(p-1) pre ; idle post ============
    const float* w2g = net ? lw2 : mw2;
    float w2w[64];
#pragma unroll
    for (int q = 0; q < 64; ++q) w2w[q] = w2g[((ch*64 + q)*3 + 1)*3 + 0];
#pragma unroll
    for (int q = 0; q < 64; ++q) asm volatile("" : "+v"(w2w[q]));
#pragma unroll 1
    for (int p = 0; p < 64; ++p) {
      const int i = p >> 3, j = p & 7, cur = i & 1;
      {
        // pcol j: pad col 0 gives zero at j==0 automatically
        const float4 f = FRAG(&h1row[net][cur][j][0]);
        float a0 = 0.f, a1 = 0.f, a2 = 0.f, a3 = 0.f;
        DOT16(w2w, f);
        r2w[net][ch] = (a0 + a1) + (a2 + a3);
      }
      BAR();
      BAR();
    }
  }

  BAR();   // join: yb complete (incl. y(63))

  // copy-out: y from net-0's yb
  if (tid < 256) {
    const int c = tid >> 6, p = tid & 63;
    out[(b*4 + c)*64 + p] = yb[0][(p >> 3) + 1][(p & 7) + 1][c];
  }
}

extern "C" void kernel_launch(void* const* d_in, const int* in_sizes, int n_in,
                              void* d_out, int out_size, void* d_ws, size_t ws_size,
                              hipStream_t stream) {
  (void)in_sizes; (void)n_in; (void)out_size; (void)d_ws; (void)ws_size;
  made_ar_decode_k<<<dim3(32), dim3(NT), 0, stream>>>(
      (const float*)d_in[0],
      (const float*)d_in[1],  (const float*)d_in[2],
      (const float*)d_in[3],  (const float*)d_in[4],
      (const float*)d_in[5],  (const float*)d_in[6],
      (const float*)d_in[7],  (const float*)d_in[8],
      (const float*)d_in[9],  (const float*)d_in[10],
      (const float*)d_in[11], (const float*)d_in[12],
      (const float*)d_in[13], (const float*)d_in[14],
      (const float*)d_in[15], (const float*)d_in[16],
      (float*)d_out);
}

// Round 13
// 223.752 us; speedup vs baseline: 1.1132x; 1.1132x over previous
//
#include <hip/hip_runtime.h>

// MADE / PixelCNN autoregressive inverse (all fp32, per reference).
//
// Ledger: r0-r4 6-bar/16-wave ~191-179us (inner-loop invariant). r7
// 2-bar/8-wave spine+helpers 146.5. r9 DOTU==readlane -> MAC style
// irrelevant. r10 2-wave deep chain 229 -> chain stays on one wave. r11
// availability-rebalanced helpers 137.8 (best; WRITE 33KB). r12 12-wave
// 1-dot-per-phase flattening: bit-exact but 176us -- the asm "+v" pins
// demanded 128 ARCHITECTURAL VGPRs while waves_per_eu(3,3) splits the
// 170-reg budget ~84 VGPR + ~84 AGPR (VGPR_Count=84) -> forced scratch
// spills (WRITE 5.6MB). The pins date from the falsified r2 load-sinking
// theory; r0-r4 proved the allocator parks invariant weight arrays in
// AGPRs naturally (unified file, direct v_fmac operands, zero cost).
//
// r13 = r12 with ALL pins removed. Same math (r12 was absmax 0.0), same
// schedule: 12 waves (3/SIMD), per net: S, T(twin), H0,H1,H2, H4.
//  S : pre: epi(p-1) [y in-reg], h0(p), c1-halfA (readlane q0..7 on own h0v)
//      post: h1 = elu(c1A+c1B+b + 4 W1 partials), c2 (readlane), h2,
//            butterfly, xchg, lsacc.
//  T : pre: epi+h0 CLONES (identical inputs/op order -> bit-identical h0v),
//      c1-halfB (q8..15) -> c1h.
//      post: W1-W . h0(p) for p+1 via readlane on own h0v -> r1w[(p+1)&1].
//  Hk (k=0,1,2 = NW,N,NE): pre: W2(k) . h1row[prv][j+k] -> r2n[k]
//      post: W1(k) . h0row[sp][j2+k] for p+1 -> r1n[k][(p+1)&1]  (i2>=1)
//  H4: pre: W2-W . h1row[cur][j] (pad col 0 -> auto-zero at j==0) -> r2w.
// Max phase = 1 dot + small chain; W1 partials parity-double-buffered,
// W2 partials + c1h single-buffered.

#define NT 768

__device__ __forceinline__ float elu(float x) { return x > 0.f ? x : expm1f(x); }

__device__ __forceinline__ float rdlane(float v, int l) {
  return __int_as_float(__builtin_amdgcn_readlane(__float_as_int(v), l));
}

#define BAR() asm volatile("s_waitcnt lgkmcnt(0)\n\ts_barrier" ::: "memory")

// one 64-dot: acc{0..3} += W_[4q+m] * (lane-q broadcast of F_ members)
#define DOT16(W_, F_)                                                \
  _Pragma("unroll")                                                  \
  for (int q = 0; q < 16; ++q) {                                     \
    a0 += (W_)[4*q+0] * rdlane((F_).x, q);                           \
    a1 += (W_)[4*q+1] * rdlane((F_).y, q);                           \
    a2 += (W_)[4*q+2] * rdlane((F_).z, q);                           \
    a3 += (W_)[4*q+3] * rdlane((F_).w, q);                           \
  }

#define FRAG(P_) (reinterpret_cast<const float4*>(P_)[ch & 15])

// shared epilogue math for S and T (identical op order -> identical bits)
#define EPI_CALC(PP_)                                                            \
  const float4 m4 = *reinterpret_cast<const float4*>(&xchg[(PP_) & 1][0][0]);    \
  const float4 l4 = *reinterpret_cast<const float4*>(&xchg[(PP_) & 1][1][0]);    \
  const float ls0 = 0.5f*(l4.x + boL[0]), ls1 = 0.5f*(l4.y + boL[1]);            \
  const float ls2 = 0.5f*(l4.z + boL[2]), ls3 = 0.5f*(l4.w + boL[3]);            \
  y0 = (xls[0*64+(PP_)] - (m4.x + boM[0])) / (expf(ls0) + 1e-12f);               \
  y1 = (xls[1*64+(PP_)] - (m4.y + boM[1])) / (expf(ls1) + 1e-12f);               \
  y2 = (xls[2*64+(PP_)] - (m4.z + boM[2])) / (expf(ls2) + 1e-12f);               \
  y3 = (xls[3*64+(PP_)] - (m4.w + boM[3])) / (expf(ls3) + 1e-12f);

// h0 from yb N-taps + in-register W-tap (identical for S and T)
#define H0_CALC()                                                                \
  float acc = bA;                                                                \
  {                                                                              \
    const float4 yNW = *reinterpret_cast<const float4*>(&yb[net][i][j    ][0]);  \
    const float4 yN  = *reinterpret_cast<const float4*>(&yb[net][i][j + 1][0]);  \
    const float4 yNE = *reinterpret_cast<const float4*>(&yb[net][i][j + 2][0]);  \
    acc += w0t[0]*yNW.x + w0t[1]*yNW.y + w0t[2]*yNW.z + w0t[3]*yNW.w;            \
    acc += w0t[4]*yN.x  + w0t[5]*yN.y  + w0t[6]*yN.z  + w0t[7]*yN.w;             \
    acc += w0t[8]*yNE.x + w0t[9]*yNE.y + w0t[10]*yNE.z + w0t[11]*yNE.w;          \
    if (j > 0) acc += w0t[12]*y0 + w0t[13]*y1 + w0t[14]*y2 + w0t[15]*y3;         \
  }                                                                              \
  const float h0v = elu(acc);

__global__ __launch_bounds__(NT)
__attribute__((amdgpu_waves_per_eu(3, 3)))
void made_ar_decode_k(
    const float* __restrict__ x,
    const float* __restrict__ mw0, const float* __restrict__ mb0,
    const float* __restrict__ mw1, const float* __restrict__ mb1,
    const float* __restrict__ mw2, const float* __restrict__ mb2,
    const float* __restrict__ mwo, const float* __restrict__ mbo,
    const float* __restrict__ lw0, const float* __restrict__ lb0,
    const float* __restrict__ lw1, const float* __restrict__ lb1,
    const float* __restrict__ lw2, const float* __restrict__ lb2,
    const float* __restrict__ lwo, const float* __restrict__ lbo,
    float* __restrict__ out)
{
  const int b    = blockIdx.x;
  const int tid  = threadIdx.x;
  const int wv   = tid >> 6;       // 0..11
  const int net  = wv & 1;         // 0 = mu, 1 = lv
  const int role = wv >> 1;        // 0:S 1:T 2:H0 3:H1 4:H2 5:H4
  const int ch   = tid & 63;       // lane == out channel

  // parity double-buffered row caches; pcol = spatial col + 1; pad cols 0,9
  // never written -> permanent zeros ('SAME' border).
  __shared__ __align__(16) float h0row[2][2][10][64]; // [net][par][pcol][ch]
  __shared__ __align__(16) float h1row[2][2][10][64];
  __shared__ __align__(16) float yb[2][9][10][4];     // [net][prow][pcol][c]
  __shared__ __align__(16) float xchg[2][2][4];       // [p&1][net][c]
  __shared__ float c1h[2][64];                        // T's c1 half (q8..15)
  __shared__ float r1n[3][2][2][64];  // W1 {NW,N,NE} [tap][pix&1][net][ch]
  __shared__ float r1w[2][2][64];     // W1 W         [pix&1][net][ch]
  __shared__ float r2n[3][2][64];     // W2 {NW,N,NE} [tap][net][ch]
  __shared__ float r2w[2][64];        // W2 W         [net][ch]
  __shared__ float xls[256];

  for (int k = tid; k < 2*2*10*64; k += NT) {
    (&h0row[0][0][0][0])[k] = 0.f;
    (&h1row[0][0][0][0])[k] = 0.f;
  }
  for (int k = tid; k < 2*9*10*4; k += NT) (&yb[0][0][0][0])[k] = 0.f;
  for (int k = tid; k < 3*2*2*64; k += NT) (&r1n[0][0][0][0])[k] = 0.f;
  for (int k = tid; k < 2*2*64; k += NT) (&r1w[0][0][0])[k] = 0.f;
  if (tid < 256) xls[tid] = x[b*256 + tid];   // [c][i][j] flat = c*64 + p

  __syncthreads();   // uniform join after init

  if (role == 0) {
    // ================= S: serial spine =================
    const float* w0g = net ? lw0 : mw0;
    const float* w1g = net ? lw1 : mw1;
    const float* w2g = net ? lw2 : mw2;
    const float* wog = net ? lwo : mwo;
    float w0t[16], wc1a[32], wc2[64], wo4[4];
    {
      const int KH[4] = {0,0,0,1};
      const int KW[4] = {0,1,2,0};
#pragma unroll
      for (int t = 0; t < 4; ++t)
#pragma unroll
        for (int ic = 0; ic < 4; ++ic)
          w0t[t*4+ic] = w0g[((ch*4 + ic)*3 + KH[t])*3 + KW[t]];
    }
#pragma unroll
    for (int q = 0; q < 32; ++q) wc1a[q] = w1g[((ch*64 + q)*3 + 1)*3 + 1];
#pragma unroll
    for (int q = 0; q < 64; ++q) wc2[q] = w2g[((ch*64 + q)*3 + 1)*3 + 1];
#pragma unroll
    for (int c = 0; c < 4; ++c) wo4[c] = wog[c*64 + ch];
    const float bA = (net ? lb0 : mb0)[ch];
    const float bB = (net ? lb1 : mb1)[ch];
    const float bC = (net ? lb2 : mb2)[ch];
    float boM[4], boL[4];
#pragma unroll
    for (int c = 0; c < 4; ++c) { boM[c] = mbo[c]; boL[c] = lbo[c]; }

    float y0 = 0.f, y1 = 0.f, y2 = 0.f, y3 = 0.f;
    float lsacc = 0.f;

#pragma unroll 1
    for (int p = 0; p < 64; ++p) {
      const int i = p >> 3, j = p & 7, cur = i & 1, pb = p & 1;

      // ---- pre-B1: epi(p-1), h0(p), c1-halfA ----
      if (p > 0) {
        const int pp = p - 1;
        EPI_CALC(pp);
        if (ch == 0)
          *reinterpret_cast<float4*>(&yb[net][(pp>>3)+1][(pp&7)+1][0]) =
              make_float4(y0, y1, y2, y3);
      }
      H0_CALC();
      h0row[net][cur][j + 1][ch] = h0v;

      float c1A;
      {
        float a0 = 0.f, a1 = 0.f, a2 = 0.f, a3 = 0.f;
#pragma unroll
        for (int q = 0; q < 8; ++q) {
          a0 += wc1a[4*q+0] * rdlane(h0v, 4*q+0);
          a1 += wc1a[4*q+1] * rdlane(h0v, 4*q+1);
          a2 += wc1a[4*q+2] * rdlane(h0v, 4*q+2);
          a3 += wc1a[4*q+3] * rdlane(h0v, 4*q+3);
        }
        c1A = (a0 + a1) + (a2 + a3);
      }

      BAR();   // B1

      // ---- post-B1: h1, c2, h2, out-conv ----
      const float c1 = c1A + c1h[net][ch];
      const float h1v = elu(((c1 + bB) + (r1n[0][pb][net][ch] + r1n[1][pb][net][ch]))
                            + (r1n[2][pb][net][ch] + r1w[pb][net][ch]));
      h1row[net][cur][j + 1][ch] = h1v;

      float c2;
      {
        float a0 = 0.f, a1 = 0.f, a2 = 0.f, a3 = 0.f;
#pragma unroll
        for (int q = 0; q < 16; ++q) {
          a0 += wc2[4*q+0] * rdlane(h1v, 4*q+0);
          a1 += wc2[4*q+1] * rdlane(h1v, 4*q+1);
          a2 += wc2[4*q+2] * rdlane(h1v, 4*q+2);
          a3 += wc2[4*q+3] * rdlane(h1v, 4*q+3);
        }
        c2 = (a0 + a1) + (a2 + a3);
      }
      const float h2v = elu(((c2 + bC) + (r2n[0][net][ch] + r2n[1][net][ch]))
                            + (r2n[2][net][ch] + r2w[net][ch]));

      float s0 = wo4[0]*h2v, s1 = wo4[1]*h2v, s2 = wo4[2]*h2v, s3 = wo4[3]*h2v;
#pragma unroll
      for (int off = 32; off; off >>= 1) {
        s0 += __shfl_xor(s0, off, 64);
        s1 += __shfl_xor(s1, off, 64);
        s2 += __shfl_xor(s2, off, 64);
        s3 += __shfl_xor(s3, off, 64);
      }
      if (ch == 0)
        *reinterpret_cast<float4*>(&xchg[p & 1][net][0]) = make_float4(s0, s1, s2, s3);
      if (net == 1 && ch == 0)
        lsacc += 0.5f*((s0 + boL[0]) + (s1 + boL[1]) + (s2 + boL[2]) + (s3 + boL[3]));

      BAR();   // B2
    }

    // final y(63) into yb (for the copy-out)
    {
      float y0f, y1f, y2f, y3f;
      {
        float y0, y1, y2, y3;
        EPI_CALC(63);
        y0f = y0; y1f = y1; y2f = y2; y3f = y3;
      }
      if (ch == 0)
        *reinterpret_cast<float4*>(&yb[net][8][8][0]) = make_float4(y0f, y1f, y2f, y3f);
    }
    if (net == 1 && ch == 0) out[32*4*64 + b] = lsacc;

  } else if (role == 1) {
    // ============ T: twin (epi+h0 clones, c1-halfB, W1-W tap) ============
    const float* w0g = net ? lw0 : mw0;
    const float* w1g = net ? lw1 : mw1;
    float w0t[16], wc1b[32], w1w[64];
    {
      const int KH[4] = {0,0,0,1};
      const int KW[4] = {0,1,2,0};
#pragma unroll
      for (int t = 0; t < 4; ++t)
#pragma unroll
        for (int ic = 0; ic < 4; ++ic)
          w0t[t*4+ic] = w0g[((ch*4 + ic)*3 + KH[t])*3 + KW[t]];
    }
#pragma unroll
    for (int q = 0; q < 32; ++q) wc1b[q] = w1g[((ch*64 + (32+q))*3 + 1)*3 + 1];
#pragma unroll
    for (int q = 0; q < 64; ++q) w1w[q] = w1g[((ch*64 + q)*3 + 1)*3 + 0];
    const float bA = (net ? lb0 : mb0)[ch];
    float boM[4], boL[4];
#pragma unroll
    for (int c = 0; c < 4; ++c) { boM[c] = mbo[c]; boL[c] = lbo[c]; }

    float y0 = 0.f, y1 = 0.f, y2 = 0.f, y3 = 0.f;

#pragma unroll 1
    for (int p = 0; p < 64; ++p) {
      const int i = p >> 3, j = p & 7;

      // ---- pre-B1: epi/h0 clones (bit-identical to S), c1-halfB ----
      if (p > 0) { const int pp = p - 1; EPI_CALC(pp); }
      H0_CALC();

      {
        float a0 = 0.f, a1 = 0.f, a2 = 0.f, a3 = 0.f;
#pragma unroll
        for (int q = 0; q < 8; ++q) {
          a0 += wc1b[4*q+0] * rdlane(h0v, 32 + 4*q+0);
          a1 += wc1b[4*q+1] * rdlane(h0v, 32 + 4*q+1);
          a2 += wc1b[4*q+2] * rdlane(h0v, 32 + 4*q+2);
          a3 += wc1b[4*q+3] * rdlane(h0v, 32 + 4*q+3);
        }
        c1h[net][ch] = (a0 + a1) + (a2 + a3);
      }

      BAR();   // B1

      // ---- post-B1: W1-W . h0(p) for p+1 (own registers) ----
      if (p < 63) {
        const int p2 = p + 1, j2 = p2 & 7;
        float v = 0.f;
        if (j2 > 0) {
          float a0 = 0.f, a1 = 0.f, a2 = 0.f, a3 = 0.f;
#pragma unroll
          for (int q = 0; q < 16; ++q) {
            a0 += w1w[4*q+0] * rdlane(h0v, 4*q+0);
            a1 += w1w[4*q+1] * rdlane(h0v, 4*q+1);
            a2 += w1w[4*q+2] * rdlane(h0v, 4*q+2);
            a3 += w1w[4*q+3] * rdlane(h0v, 4*q+3);
          }
          v = (a0 + a1) + (a2 + a3);
        }
        r1w[p2 & 1][net][ch] = v;
      }

      BAR();   // B2
    }

  } else if (role <= 4) {
    // ============ Hk (k = role-2): W2(k) pre ; W1(k) post for p+1 ============
    const int tap = role - 2;        // 0:NW 1:N 2:NE
    const float* w1g = net ? lw1 : mw1;
    const float* w2g = net ? lw2 : mw2;
    float w2c[64], w1c[64];
#pragma unroll
    for (int q = 0; q < 64; ++q) {
      w2c[q] = w2g[((ch*64 + q)*3 + 0)*3 + tap];
      w1c[q] = w1g[((ch*64 + q)*3 + 0)*3 + tap];
    }
#pragma unroll 1
    for (int p = 0; p < 64; ++p) {
      const int i = p >> 3, j = p & 7, prv = (i & 1) ^ 1;
      {
        const float4 f = FRAG(&h1row[net][prv][j + tap][0]);
        float a0 = 0.f, a1 = 0.f, a2 = 0.f, a3 = 0.f;
        DOT16(w2c, f);
        r2n[tap][net][ch] = (a0 + a1) + (a2 + a3);
      }
      BAR();
      if (p < 63) {
        const int p2 = p + 1, i2 = p2 >> 3, j2 = p2 & 7;
        float v = 0.f;
        if (i2 >= 1) {
          const int sp = (i2 - 1) & 1;
          const float4 f = FRAG(&h0row[net][sp][j2 + tap][0]);
          float a0 = 0.f, a1 = 0.f, a2 = 0.f, a3 = 0.f;
          DOT16(w1c, f);
          v = (a0 + a1) + (a2 + a3);
        }
        r1n[tap][p2 & 1][net][ch] = v;
      }
      BAR();
    }

  } else {
    // ============ H4: W2-W . h1(p-1) pre ; idle post ============
    const float* w2g = net ? lw2 : mw2;
    float w2w[64];
#pragma unroll
    for (int q = 0; q < 64; ++q) w2w[q] = w2g[((ch*64 + q)*3 + 1)*3 + 0];
#pragma unroll 1
    for (int p = 0; p < 64; ++p) {
      const int i = p >> 3, j = p & 7, cur = i & 1;
      {
        // pcol j: pad col 0 gives zero at j==0 automatically
        const float4 f = FRAG(&h1row[net][cur][j][0]);
        float a0 = 0.f, a1 = 0.f, a2 = 0.f, a3 = 0.f;
        DOT16(w2w, f);
        r2w[net][ch] = (a0 + a1) + (a2 + a3);
      }
      BAR();
      BAR();
    }
  }

  BAR();   // join: yb complete (incl. y(63))

  // copy-out: y from net-0's yb
  if (tid < 256) {
    const int c = tid >> 6, p = tid & 63;
    out[(b*4 + c)*64 + p] = yb[0][(p >> 3) + 1][(p & 7) + 1][c];
  }
}

extern "C" void kernel_launch(void* const* d_in, const int* in_sizes, int n_in,
                              void* d_out, int out_size, void* d_ws, size_t ws_size,
                              hipStream_t stream) {
  (void)in_sizes; (void)n_in; (void)out_size; (void)d_ws; (void)ws_size;
  made_ar_decode_k<<<dim3(32), dim3(NT), 0, stream>>>(
      (const float*)d_in[0],
      (const float*)d_in[1],  (const float*)d_in[2],
      (const float*)d_in[3],  (const float*)d_in[4],
      (const float*)d_in[5],  (const float*)d_in[6],
      (const float*)d_in[7],  (const float*)d_in[8],
      (const float*)d_in[9],  (const float*)d_in[10],
      (const float*)d_in[11], (const float*)d_in[12],
      (const float*)d_in[13], (const float*)d_in[14],
      (const float*)d_in[15], (const float*)d_in[16],
      (float*)d_out);
}